// Round 9
// baseline (795.244 us; speedup 1.0000x reference)
//
#include <hip/hip_runtime.h>
#include <cstdint>

// ---------------------------------------------------------------------------
// DDPM + VAE query encoder, MI355X round 21.
// r20 post-mortem: specialization overlapped noise+GEMV but packing stuck at
// ~38% (2050 cy issue vs 5330 cy/step per SIMD) -- only 4 waves/SIMD (grid
// 512 = 2 blocks/CU). r21: 8 rows/block -> 1024 blocks -> 4 blocks/CU ->
// 8 waves/SIMD (full occupancy).
//  - MFMA A-rows 8-15 are garbage; C rows depend only on same A row -> never
//    stored, harmless; MFMA count/block unchanged (it's cheap at 8% util).
//  - noise waves: 2 draws/thread/step (was 4) -> shorter chains/segment.
//  - role = (w ^ (w>>2)) & 1: balanced GEMV:noise mix under BOTH plausible
//    wave->SIMD mappings (w&3 and w>>1).
//  - waves_per_eu(8): 64-VGPR budget (r20 used 52). Spill tripwire:
//    WRITE_SIZE >> 2 MB.
// Same threefry bits via LDS -> absmax unchanged.
// ---------------------------------------------------------------------------

#define DEVI __device__ __forceinline__

typedef __attribute__((ext_vector_type(8))) short short8;
typedef __attribute__((ext_vector_type(4))) float f32x4;

DEVI void threefry2x32(uint32_t k0, uint32_t k1, uint32_t x0, uint32_t x1,
                       uint32_t &o0, uint32_t &o1)
{
  const uint32_t ks2 = k0 ^ k1 ^ 0x1BD11BDAu;
  x0 += k0; x1 += k1;
#define TFR(r) { x0 += x1; x1 = __builtin_rotateleft32(x1, r); x1 ^= x0; }
  TFR(13u) TFR(15u) TFR(26u) TFR(6u)   x0 += k1;  x1 += ks2 + 1u;
  TFR(17u) TFR(29u) TFR(16u) TFR(24u)  x0 += ks2; x1 += k0 + 2u;
  TFR(13u) TFR(15u) TFR(26u) TFR(6u)   x0 += k0;  x1 += k1 + 3u;
  TFR(17u) TFR(29u) TFR(16u) TFR(24u)  x0 += k1;  x1 += ks2 + 4u;
  TFR(13u) TFR(15u) TFR(26u) TFR(6u)   x0 += ks2; x1 += k0 + 5u;
#undef TFR
  o0 = x0; o1 = x1;
}

DEVI uint32_t jax_random_bits32(uint32_t k0, uint32_t k1, uint32_t j)
{
  uint32_t a, b;
  threefry2x32(k0, k1, 0u, j, a, b);
  return a ^ b;
}

DEVI float jax_bits_to_normal(uint32_t bits)
{
  const float LO = -0.99999994f;
  float f = __uint_as_float((bits >> 9) | 0x3f800000u) - 1.0f;
  float u = fmaxf(LO, f * 2.0f + LO);
  float w = -__logf((1.0f - u) * (1.0f + u));
  float p;
  if (w < 5.0f) {
    w = w - 2.5f;
    p =              2.81022636e-08f;
    p = fmaf(p, w,   3.43273939e-07f);
    p = fmaf(p, w,  -3.5233877e-06f);
    p = fmaf(p, w,  -4.39150654e-06f);
    p = fmaf(p, w,   0.00021858087f);
    p = fmaf(p, w,  -0.00125372503f);
    p = fmaf(p, w,  -0.00417768164f);
    p = fmaf(p, w,   0.246640727f);
    p = fmaf(p, w,   1.50140941f);
  } else {
    w = sqrtf(w) - 3.0f;
    p =             -0.000200214257f;
    p = fmaf(p, w,   0.000100950558f);
    p = fmaf(p, w,   0.00134934322f);
    p = fmaf(p, w,  -0.00367342844f);
    p = fmaf(p, w,   0.00573950773f);
    p = fmaf(p, w,  -0.0076224613f);
    p = fmaf(p, w,   0.00943887047f);
    p = fmaf(p, w,   1.00167406f);
    p = fmaf(p, w,   2.83297682f);
  }
  return 1.41421356237f * (p * u);
}

DEVI short bf16_hi_trunc(float x) { return (short)(__float_as_uint(x) >> 16); }
DEVI float bf16_to_f32(short h)
{
  return __uint_as_float(((uint32_t)(unsigned short)h) << 16);
}
DEVI void split_bf16(float x, short &h, short &l)
{
  h = bf16_hi_trunc(x);
  float r = x - bf16_to_f32(h);
  l = bf16_hi_trunc(r);
}

// 8-short fragment from 16B-aligned LDS (stride-72 rows): one b128 read.
DEVI short8 ld_frag16(const short* p)
{
  union { int4 v; short8 s; } u;
  u.v = *(const int4*)p;
  return u.s;
}

// ---------------------------------------------------------------------------
__global__ __launch_bounds__(256)
void k_pool(const int* __restrict__ seq, const float* __restrict__ emb,
            float* __restrict__ pooled)
{
  const int lane = threadIdx.x & 63;
  const int r    = blockIdx.x * 4 + (threadIdx.x >> 6);
  const int* row = seq + r * 100;
  float s = 0.f;
  int cnt = 0;
  for (int l = 0; l < 100; ++l) {
    int id = row[l];
    cnt += (id != 0);
    s += emb[id * 64 + lane];
  }
  pooled[r * 64 + lane] = s / sqrtf((float)cnt);
}

// ---------------------------------------------------------------------------
__global__ __launch_bounds__(256)
void k_enc(const float* __restrict__ pooled,
           const float* __restrict__ W1, const float* __restrict__ b1,
           const float* __restrict__ W2, const float* __restrict__ b2,
           const float* __restrict__ Wc, const float* __restrict__ bc,
           float* __restrict__ cproj)
{
  __shared__ float p_s[8][64];
  __shared__ float h_s[8][256];
  __shared__ float mu_s[8][64];
  const int tid = threadIdx.x;
  const int r0  = blockIdx.x * 8;

  for (int i = tid; i < 8 * 64; i += 256)
    p_s[i >> 6][i & 63] = pooled[r0 * 64 + i];
  __syncthreads();

  float hacc[8];
#pragma unroll
  for (int r = 0; r < 8; ++r) hacc[r] = b1[tid];
  for (int k = 0; k < 64; ++k) {
    float w = W1[k * 256 + tid];
#pragma unroll
    for (int r = 0; r < 8; ++r) hacc[r] = fmaf(p_s[r][k], w, hacc[r]);
  }
#pragma unroll
  for (int r = 0; r < 8; ++r) h_s[r][tid] = fmaxf(hacc[r], 0.f);
  __syncthreads();

#pragma unroll
  for (int pass = 0; pass < 2; ++pass) {
    int r = pass * 4 + (tid >> 6);
    int j = tid & 63;
    float acc = b2[j];
    for (int k = 0; k < 256; ++k)
      acc = fmaf(h_s[r][k], W2[k * 128 + j], acc);
    mu_s[r][j] = acc;
  }
  __syncthreads();

#pragma unroll
  for (int pass = 0; pass < 2; ++pass) {
    int r = pass * 4 + (tid >> 6);
    int j = tid & 63;
    float acc = bc[j];
    for (int k = 0; k < 64; ++k)
      acc = fmaf(mu_s[r][k], Wc[k * 64 + j], acc);
    cproj[(r0 + r) * 64 + j] = acc;
  }
}

// ---------------------------------------------------------------------------
// k_prep: 200 blocks x 64 threads. Block t computes sched[t*8+..] AND
// tpb[t][d] = temb(t)@W_t + b_t + b_in.
__global__ __launch_bounds__(64)
void k_prep(const float* __restrict__ Wt, const float* __restrict__ bt,
            const float* __restrict__ bin, float* __restrict__ tpb,
            float* __restrict__ sched)
{
  __shared__ float temb[64];
  const int t = blockIdx.x;
  const int d = threadIdx.x;
  const float lg = logf(10000.0f);
  {
    int i = d & 31;
    float fr  = expf((-lg * (float)i) / 32.0f);
    float ang = (float)t * fr;
    temb[d] = (d < 32) ? cosf(ang) : sinf(ang);
  }
  if (d == 0) {
    const float start = (float)(5.0 * 1e-4);
    const float stop  = (float)(5.0 * 0.02);
    const float delta = stop - start;
    float prod = 1.f, acp_prev = 1.f, beta = 0.f, alpha = 1.f;
    for (int i = 0; i <= t; ++i) {
      beta  = start + ((float)i * delta) / 199.0f;
      alpha = 1.0f - beta;
      acp_prev = prod;
      prod = prod * alpha;
    }
    float acp = prod;
    float om  = 1.0f - acp;
    sched[t * 8 + 0] = sqrtf(1.0f / acp);
    sched[t * 8 + 1] = sqrtf(1.0f / acp - 1.0f);
    sched[t * 8 + 2] = beta * sqrtf(acp_prev) / om;
    sched[t * 8 + 3] = (1.0f - acp_prev) * sqrtf(alpha) / om;
    float pv = beta * (1.0f - acp_prev) / om;
    sched[t * 8 + 4] = (t > 0) ? sqrtf(pv) : 0.0f;
    uint32_t fk0, fk1;
    threefry2x32(0u, 2u, 0u, (uint32_t)t, fk0, fk1);
    ((uint32_t*)sched)[t * 8 + 5] = fk0;
    ((uint32_t*)sched)[t * 8 + 6] = fk1;
  }
  __syncthreads();
  float acc = bt[d] + bin[d];
  for (int k = 0; k < 64; ++k)
    acc = fmaf(temb[k], Wt[k * 64 + d], acc);
  tpb[t * 64 + d] = acc;
}

// ---------------------------------------------------------------------------
// K_ddpm: 1024 blocks x 512 threads (8 waves). Block owns 8 rows.
// Role by (w ^ (w>>2)) & 1 == 0 -> GEMV (waves 0,2,5,7), else noise.
// GEMV wave nt in {0..3}: cols 16nt..16nt+15; lane (quad,nn): quads 0,1 own
//   rows quad*4..+3; quads 2,3 compute garbage C rows 8-15 (never stored).
// Noise waves produce step t-1's 8x64 values (2/thread: 1 before B1, 1
//   after) into nbuf[(t-1)&1] while GEMV waves compute step t.
#define XLDW  72   // X/H row stride (shorts); 144 B -> 16B-aligned frags
#define NBW   68   // nbuf row stride (floats)

__global__
__attribute__((amdgpu_flat_work_group_size(512, 512), amdgpu_waves_per_eu(8)))
void k_ddpm(const float* __restrict__ Win, const float* __restrict__ Wout,
            const float* __restrict__ bout,
            const float* __restrict__ cproj, const float* __restrict__ tpb,
            const float* __restrict__ sched, float* __restrict__ out)
{
  __shared__ __align__(16) short Xh[16 * XLDW], Xl[16 * XLDW];
  __shared__ __align__(16) short Hh[16 * XLDW], Hl[16 * XLDW];
  __shared__ __align__(16) float nbuf[2 * 8 * NBW];
  // total: 4*2304 + 4352 = 13568 B -> 4 blocks/CU fits easily

  const int tid  = threadIdx.x;
  const int lane = tid & 63;
  const int w    = tid >> 6;
  const bool gemv = ((w ^ (w >> 2)) & 1) == 0;   // waves 0,2,5,7
  const int r0g  = blockIdx.x * 8;
  const uint32_t* su = (const uint32_t*)sched;

  // ---- GEMV-wave ids (col group among the 4 GEMV waves)
  const int nt   = (w == 0) ? 0 : (w == 2) ? 1 : (w == 5) ? 2 : 3;
  const int nn   = lane & 15;
  const int quad = lane >> 4;
  const int dim  = nt * 16 + nn;
  const int arow = nn;
  const int kq0  = quad * 8;
  const int kq1  = 32 + quad * 8;
  const bool own = (quad < 2);                   // rows 0-7 only
  const int rowb = own ? quad * 4 : 0;           // owned rows rowb..rowb+3

  // ---- noise-wave ids (index among the 4 noise waves): 2 cells/thread
  const int ni   = (w == 1) ? 0 : (w == 3) ? 1 : (w == 4) ? 2 : 3;
  const int q    = ni * 64 + lane;               // [0,256)
  const int cb   = q * 2;                        // cell base (row*64+dim)
  const uint32_t jn = (uint32_t)(r0g * 64 + cb);
  const int nrow = cb >> 6;
  const int ndim = cb & 63;
  float* nb_w = &nbuf[nrow * NBW + ndim];        // + buf*8*NBW at use

  // ---- GEMV state
  short8 wiH0, wiL0, wiH1, wiL1, woH0, woL0, woH1, woL1;
  float cp[4] = {0.f, 0.f, 0.f, 0.f}, xo[4] = {0.f, 0.f, 0.f, 0.f};
  float bo = 0.f, tp = 0.f;
  uint32_t j0 = 0;

  if (gemv) {
#pragma unroll
    for (int j = 0; j < 8; ++j) {
      short h, l;
      split_bf16(Win[(kq0 + j) * 64 + dim], h, l);  wiH0[j] = h; wiL0[j] = l;
      split_bf16(Win[(kq1 + j) * 64 + dim], h, l);  wiH1[j] = h; wiL1[j] = l;
      split_bf16(Wout[(kq0 + j) * 64 + dim], h, l); woH0[j] = h; woL0[j] = l;
      split_bf16(Wout[(kq1 + j) * 64 + dim], h, l); woH1[j] = h; woL1[j] = l;
    }
    bo = bout[dim];
    j0 = (uint32_t)((r0g + rowb) * 64 + dim);    // rowb clamped for !own
    if (own) {
#pragma unroll
      for (int r = 0; r < 4; ++r) cp[r] = cproj[j0 + r * 64u];
#pragma unroll
      for (int r = 0; r < 4; ++r) {
        xo[r] = jax_bits_to_normal(jax_random_bits32(0u, 1u, j0 + r * 64u));
        short h, l;
        split_bf16(xo[r], h, l);
        Xh[(rowb + r) * XLDW + dim] = h; Xl[(rowb + r) * XLDW + dim] = l;
      }
    }
    tp = tpb[199 * 64 + dim];
  } else {
    // prologue: noise for t=199 into nbuf[1]
    const uint32_t fk0 = su[199 * 8 + 5];
    const uint32_t fk1 = su[199 * 8 + 6];
    float* d = nb_w + 8 * NBW;                   // buf 1
    d[0] = jax_bits_to_normal(jax_random_bits32(fk0, fk1, jn + 0u));
    d[1] = jax_bits_to_normal(jax_random_bits32(fk0, fk1, jn + 1u));
  }
  __syncthreads();

#pragma unroll 1
  for (int t = 199; t >= 0; --t) {
    float sr = 0.f, srm1 = 0.f, c1 = 0.f, c2 = 0.f, sg = 0.f;
    float n[4], tpn = 0.f;
    f32x4 acc;
    uint32_t gk0 = 0, gk1 = 0;
    float* nd = nullptr;

    if (gemv) {
      sr   = sched[t * 8 + 0];
      srm1 = sched[t * 8 + 1];
      c1   = sched[t * 8 + 2];
      c2   = sched[t * 8 + 3];
      sg   = sched[t * 8 + 4];
      // noise for this step (produced >= one barrier-pair ago)
      const float* nr = &nbuf[(t & 1) * 8 * NBW + rowb * NBW + dim];
#pragma unroll
      for (int r = 0; r < 4; ++r) n[r] = nr[r * NBW];

      // ---- phase A: in-GEMV, full K=64
#pragma unroll
      for (int r = 0; r < 4; ++r) acc[r] = tp + cp[r];
      {
        short8 xh0 = ld_frag16(&Xh[arow * XLDW + kq0]);
        short8 xl0 = ld_frag16(&Xl[arow * XLDW + kq0]);
        short8 xh1 = ld_frag16(&Xh[arow * XLDW + kq1]);
        short8 xl1 = ld_frag16(&Xl[arow * XLDW + kq1]);
        acc = __builtin_amdgcn_mfma_f32_16x16x32_bf16(xl0, wiH0, acc, 0, 0, 0);
        acc = __builtin_amdgcn_mfma_f32_16x16x32_bf16(xh0, wiL0, acc, 0, 0, 0);
        acc = __builtin_amdgcn_mfma_f32_16x16x32_bf16(xh0, wiH0, acc, 0, 0, 0);
        acc = __builtin_amdgcn_mfma_f32_16x16x32_bf16(xl1, wiH1, acc, 0, 0, 0);
        acc = __builtin_amdgcn_mfma_f32_16x16x32_bf16(xh1, wiL1, acc, 0, 0, 0);
        acc = __builtin_amdgcn_mfma_f32_16x16x32_bf16(xh1, wiH1, acc, 0, 0, 0);
      }
      if (own) {
#pragma unroll
        for (int r = 0; r < 4; ++r) {
          float v = acc[r];
          v = v * __builtin_amdgcn_rcpf(1.0f + __expf(-v));
          short h, l;
          split_bf16(v, h, l);
          Hh[(rowb + r) * XLDW + dim] = h; Hl[(rowb + r) * XLDW + dim] = l;
        }
      }
      int tn = (t > 0) ? (t - 1) : 0;
      tpn = tpb[tn * 64 + dim];                  // prefetch next tp
    } else if (t > 0) {
      // noise for step t-1, first value
      gk0 = su[(t - 1) * 8 + 5];
      gk1 = su[(t - 1) * 8 + 6];
      nd = nb_w + ((t - 1) & 1) * 8 * NBW;
      nd[0] = jax_bits_to_normal(jax_random_bits32(gk0, gk1, jn + 0u));
    }
    __syncthreads();                              // B1

    if (gemv) {
      // ---- phase B: out-GEMV, full K=64, update 4 cells, restage X
      f32x4 eac;
#pragma unroll
      for (int r = 0; r < 4; ++r) eac[r] = bo;
      {
        short8 hh0 = ld_frag16(&Hh[arow * XLDW + kq0]);
        short8 hl0 = ld_frag16(&Hl[arow * XLDW + kq0]);
        short8 hh1 = ld_frag16(&Hh[arow * XLDW + kq1]);
        short8 hl1 = ld_frag16(&Hl[arow * XLDW + kq1]);
        eac = __builtin_amdgcn_mfma_f32_16x16x32_bf16(hl0, woH0, eac, 0, 0, 0);
        eac = __builtin_amdgcn_mfma_f32_16x16x32_bf16(hh0, woL0, eac, 0, 0, 0);
        eac = __builtin_amdgcn_mfma_f32_16x16x32_bf16(hh0, woH0, eac, 0, 0, 0);
        eac = __builtin_amdgcn_mfma_f32_16x16x32_bf16(hl1, woH1, eac, 0, 0, 0);
        eac = __builtin_amdgcn_mfma_f32_16x16x32_bf16(hh1, woL1, eac, 0, 0, 0);
        eac = __builtin_amdgcn_mfma_f32_16x16x32_bf16(hh1, woH1, eac, 0, 0, 0);
      }
      if (own) {
#pragma unroll
        for (int r = 0; r < 4; ++r) {
          float xc = fminf(1.f, fmaxf(-1.f, sr * xo[r] - srm1 * eac[r]));
          xo[r] = c1 * xc + c2 * xo[r] + sg * n[r];
          short h, l;
          split_bf16(xo[r], h, l);
          Xh[(rowb + r) * XLDW + dim] = h; Xl[(rowb + r) * XLDW + dim] = l;
        }
      }
      tp = tpn;
    } else if (t > 0) {
      // noise for step t-1, second value
      nd[1] = jax_bits_to_normal(jax_random_bits32(gk0, gk1, jn + 1u));
    }
    __syncthreads();                              // B2
  }

  if (gemv && own) {
#pragma unroll
    for (int r = 0; r < 4; ++r) out[j0 + r * 64u] = xo[r];
  }
}

// ---------------------------------------------------------------------------
extern "C" void kernel_launch(void* const* d_in, const int* in_sizes, int n_in,
                              void* d_out, int out_size, void* d_ws, size_t ws_size,
                              hipStream_t stream)
{
  const int*   seq  = (const int*)  d_in[0];
  const float* emb  = (const float*)d_in[1];
  const float* W1   = (const float*)d_in[2];
  const float* b1   = (const float*)d_in[3];
  const float* W2   = (const float*)d_in[4];
  const float* b2   = (const float*)d_in[5];
  const float* Win  = (const float*)d_in[6];
  const float* bin  = (const float*)d_in[7];
  const float* Wt   = (const float*)d_in[8];
  const float* bt   = (const float*)d_in[9];
  const float* Wc   = (const float*)d_in[10];
  const float* bc   = (const float*)d_in[11];
  const float* Wout = (const float*)d_in[12];
  const float* bout = (const float*)d_in[13];

  float* out   = (float*)d_out;
  float* ws    = (float*)d_ws;
  float* cproj = ws;                       // 524288 floats
  float* tpb   = ws + 524288;              // 12800 floats
  float* sched = ws + 524288 + 12800;      // 1600 floats (t*8 layout)
  float* pooled = out;                     // reuse d_out as scratch

  k_pool <<<2048, 256, 0, stream>>>(seq, emb, pooled);
  k_enc  <<<1024, 256, 0, stream>>>(pooled, W1, b1, W2, b2, Wc, bc, cproj);
  k_prep <<<200, 64, 0, stream>>>(Wt, bt, bin, tpb, sched);
  k_ddpm <<<1024, 512, 0, stream>>>(Win, Wout, bout, cproj, tpb, sched, out);
}

// Round 10
// 653.066 us; speedup vs baseline: 1.2177x; 1.2177x over previous
//
#include <hip/hip_runtime.h>
#include <cstdint>

// ---------------------------------------------------------------------------
// DDPM + VAE query encoder, MI355X round 22.
// r21 post-mortem: waves_per_eu(8) -> VGPR 32 -> scratch spills (FETCH 110MB,
// WRITE 78MB) -> 721 us. SAME confound as r14; rule: this kernel needs ~52
// VGPR, never set min waves/EU above 4. Occupancy attribute only sets the
// allocator budget; RUNTIME occupancy is resource-determined. 52 VGPR <= 64
// granule -> 8 waves/SIMD admissible at the r20 register footprint.
// r22 = r21 source, ONE change: amdgpu_waves_per_eu(4, 8)
//   min 4 -> 128-VGPR budget (no spills, like r20's 52)
//   grid 1024 x 512 (4 blocks/CU, 2048 thr = cap, LDS 54KB/CU) -> 8 w/SIMD.
// Same threefry bits via LDS -> absmax unchanged.
// ---------------------------------------------------------------------------

#define DEVI __device__ __forceinline__

typedef __attribute__((ext_vector_type(8))) short short8;
typedef __attribute__((ext_vector_type(4))) float f32x4;

DEVI void threefry2x32(uint32_t k0, uint32_t k1, uint32_t x0, uint32_t x1,
                       uint32_t &o0, uint32_t &o1)
{
  const uint32_t ks2 = k0 ^ k1 ^ 0x1BD11BDAu;
  x0 += k0; x1 += k1;
#define TFR(r) { x0 += x1; x1 = __builtin_rotateleft32(x1, r); x1 ^= x0; }
  TFR(13u) TFR(15u) TFR(26u) TFR(6u)   x0 += k1;  x1 += ks2 + 1u;
  TFR(17u) TFR(29u) TFR(16u) TFR(24u)  x0 += ks2; x1 += k0 + 2u;
  TFR(13u) TFR(15u) TFR(26u) TFR(6u)   x0 += k0;  x1 += k1 + 3u;
  TFR(17u) TFR(29u) TFR(16u) TFR(24u)  x0 += k1;  x1 += ks2 + 4u;
  TFR(13u) TFR(15u) TFR(26u) TFR(6u)   x0 += ks2; x1 += k0 + 5u;
#undef TFR
  o0 = x0; o1 = x1;
}

DEVI uint32_t jax_random_bits32(uint32_t k0, uint32_t k1, uint32_t j)
{
  uint32_t a, b;
  threefry2x32(k0, k1, 0u, j, a, b);
  return a ^ b;
}

DEVI float jax_bits_to_normal(uint32_t bits)
{
  const float LO = -0.99999994f;
  float f = __uint_as_float((bits >> 9) | 0x3f800000u) - 1.0f;
  float u = fmaxf(LO, f * 2.0f + LO);
  float w = -__logf((1.0f - u) * (1.0f + u));
  float p;
  if (w < 5.0f) {
    w = w - 2.5f;
    p =              2.81022636e-08f;
    p = fmaf(p, w,   3.43273939e-07f);
    p = fmaf(p, w,  -3.5233877e-06f);
    p = fmaf(p, w,  -4.39150654e-06f);
    p = fmaf(p, w,   0.00021858087f);
    p = fmaf(p, w,  -0.00125372503f);
    p = fmaf(p, w,  -0.00417768164f);
    p = fmaf(p, w,   0.246640727f);
    p = fmaf(p, w,   1.50140941f);
  } else {
    w = sqrtf(w) - 3.0f;
    p =             -0.000200214257f;
    p = fmaf(p, w,   0.000100950558f);
    p = fmaf(p, w,   0.00134934322f);
    p = fmaf(p, w,  -0.00367342844f);
    p = fmaf(p, w,   0.00573950773f);
    p = fmaf(p, w,  -0.0076224613f);
    p = fmaf(p, w,   0.00943887047f);
    p = fmaf(p, w,   1.00167406f);
    p = fmaf(p, w,   2.83297682f);
  }
  return 1.41421356237f * (p * u);
}

DEVI short bf16_hi_trunc(float x) { return (short)(__float_as_uint(x) >> 16); }
DEVI float bf16_to_f32(short h)
{
  return __uint_as_float(((uint32_t)(unsigned short)h) << 16);
}
DEVI void split_bf16(float x, short &h, short &l)
{
  h = bf16_hi_trunc(x);
  float r = x - bf16_to_f32(h);
  l = bf16_hi_trunc(r);
}

// 8-short fragment from 16B-aligned LDS (stride-72 rows): one b128 read.
DEVI short8 ld_frag16(const short* p)
{
  union { int4 v; short8 s; } u;
  u.v = *(const int4*)p;
  return u.s;
}

// ---------------------------------------------------------------------------
__global__ __launch_bounds__(256)
void k_pool(const int* __restrict__ seq, const float* __restrict__ emb,
            float* __restrict__ pooled)
{
  const int lane = threadIdx.x & 63;
  const int r    = blockIdx.x * 4 + (threadIdx.x >> 6);
  const int* row = seq + r * 100;
  float s = 0.f;
  int cnt = 0;
  for (int l = 0; l < 100; ++l) {
    int id = row[l];
    cnt += (id != 0);
    s += emb[id * 64 + lane];
  }
  pooled[r * 64 + lane] = s / sqrtf((float)cnt);
}

// ---------------------------------------------------------------------------
__global__ __launch_bounds__(256)
void k_enc(const float* __restrict__ pooled,
           const float* __restrict__ W1, const float* __restrict__ b1,
           const float* __restrict__ W2, const float* __restrict__ b2,
           const float* __restrict__ Wc, const float* __restrict__ bc,
           float* __restrict__ cproj)
{
  __shared__ float p_s[8][64];
  __shared__ float h_s[8][256];
  __shared__ float mu_s[8][64];
  const int tid = threadIdx.x;
  const int r0  = blockIdx.x * 8;

  for (int i = tid; i < 8 * 64; i += 256)
    p_s[i >> 6][i & 63] = pooled[r0 * 64 + i];
  __syncthreads();

  float hacc[8];
#pragma unroll
  for (int r = 0; r < 8; ++r) hacc[r] = b1[tid];
  for (int k = 0; k < 64; ++k) {
    float w = W1[k * 256 + tid];
#pragma unroll
    for (int r = 0; r < 8; ++r) hacc[r] = fmaf(p_s[r][k], w, hacc[r]);
  }
#pragma unroll
  for (int r = 0; r < 8; ++r) h_s[r][tid] = fmaxf(hacc[r], 0.f);
  __syncthreads();

#pragma unroll
  for (int pass = 0; pass < 2; ++pass) {
    int r = pass * 4 + (tid >> 6);
    int j = tid & 63;
    float acc = b2[j];
    for (int k = 0; k < 256; ++k)
      acc = fmaf(h_s[r][k], W2[k * 128 + j], acc);
    mu_s[r][j] = acc;
  }
  __syncthreads();

#pragma unroll
  for (int pass = 0; pass < 2; ++pass) {
    int r = pass * 4 + (tid >> 6);
    int j = tid & 63;
    float acc = bc[j];
    for (int k = 0; k < 64; ++k)
      acc = fmaf(mu_s[r][k], Wc[k * 64 + j], acc);
    cproj[(r0 + r) * 64 + j] = acc;
  }
}

// ---------------------------------------------------------------------------
// k_prep: 200 blocks x 64 threads. Block t computes sched[t*8+..] AND
// tpb[t][d] = temb(t)@W_t + b_t + b_in.
__global__ __launch_bounds__(64)
void k_prep(const float* __restrict__ Wt, const float* __restrict__ bt,
            const float* __restrict__ bin, float* __restrict__ tpb,
            float* __restrict__ sched)
{
  __shared__ float temb[64];
  const int t = blockIdx.x;
  const int d = threadIdx.x;
  const float lg = logf(10000.0f);
  {
    int i = d & 31;
    float fr  = expf((-lg * (float)i) / 32.0f);
    float ang = (float)t * fr;
    temb[d] = (d < 32) ? cosf(ang) : sinf(ang);
  }
  if (d == 0) {
    const float start = (float)(5.0 * 1e-4);
    const float stop  = (float)(5.0 * 0.02);
    const float delta = stop - start;
    float prod = 1.f, acp_prev = 1.f, beta = 0.f, alpha = 1.f;
    for (int i = 0; i <= t; ++i) {
      beta  = start + ((float)i * delta) / 199.0f;
      alpha = 1.0f - beta;
      acp_prev = prod;
      prod = prod * alpha;
    }
    float acp = prod;
    float om  = 1.0f - acp;
    sched[t * 8 + 0] = sqrtf(1.0f / acp);
    sched[t * 8 + 1] = sqrtf(1.0f / acp - 1.0f);
    sched[t * 8 + 2] = beta * sqrtf(acp_prev) / om;
    sched[t * 8 + 3] = (1.0f - acp_prev) * sqrtf(alpha) / om;
    float pv = beta * (1.0f - acp_prev) / om;
    sched[t * 8 + 4] = (t > 0) ? sqrtf(pv) : 0.0f;
    uint32_t fk0, fk1;
    threefry2x32(0u, 2u, 0u, (uint32_t)t, fk0, fk1);
    ((uint32_t*)sched)[t * 8 + 5] = fk0;
    ((uint32_t*)sched)[t * 8 + 6] = fk1;
  }
  __syncthreads();
  float acc = bt[d] + bin[d];
  for (int k = 0; k < 64; ++k)
    acc = fmaf(temb[k], Wt[k * 64 + d], acc);
  tpb[t * 64 + d] = acc;
}

// ---------------------------------------------------------------------------
// K_ddpm: 1024 blocks x 512 threads (8 waves). Block owns 8 rows.
// Role by (w ^ (w>>2)) & 1 == 0 -> GEMV (waves 0,2,5,7), else noise.
// GEMV wave nt in {0..3}: cols 16nt..16nt+15; lane (quad,nn): quads 0,1 own
//   rows quad*4..+3; quads 2,3 compute garbage C rows 8-15 (never stored).
// Noise waves produce step t-1's 8x64 values (2/thread: 1 before B1, 1
//   after) into nbuf[(t-1)&1] while GEMV waves compute step t.
#define XLDW  72   // X/H row stride (shorts); 144 B -> 16B-aligned frags
#define NBW   68   // nbuf row stride (floats)

__global__
__attribute__((amdgpu_flat_work_group_size(512, 512), amdgpu_waves_per_eu(4, 8)))
void k_ddpm(const float* __restrict__ Win, const float* __restrict__ Wout,
            const float* __restrict__ bout,
            const float* __restrict__ cproj, const float* __restrict__ tpb,
            const float* __restrict__ sched, float* __restrict__ out)
{
  __shared__ __align__(16) short Xh[16 * XLDW], Xl[16 * XLDW];
  __shared__ __align__(16) short Hh[16 * XLDW], Hl[16 * XLDW];
  __shared__ __align__(16) float nbuf[2 * 8 * NBW];
  // total: 4*2304 + 4352 = 13568 B -> 4 blocks/CU = 54 KB < 160 KB

  const int tid  = threadIdx.x;
  const int lane = tid & 63;
  const int w    = tid >> 6;
  const bool gemv = ((w ^ (w >> 2)) & 1) == 0;   // waves 0,2,5,7
  const int r0g  = blockIdx.x * 8;
  const uint32_t* su = (const uint32_t*)sched;

  // ---- GEMV-wave ids (col group among the 4 GEMV waves)
  const int nt   = (w == 0) ? 0 : (w == 2) ? 1 : (w == 5) ? 2 : 3;
  const int nn   = lane & 15;
  const int quad = lane >> 4;
  const int dim  = nt * 16 + nn;
  const int arow = nn;
  const int kq0  = quad * 8;
  const int kq1  = 32 + quad * 8;
  const bool own = (quad < 2);                   // rows 0-7 only
  const int rowb = own ? quad * 4 : 0;           // owned rows rowb..rowb+3

  // ---- noise-wave ids (index among the 4 noise waves): 2 cells/thread
  const int ni   = (w == 1) ? 0 : (w == 3) ? 1 : (w == 4) ? 2 : 3;
  const int q    = ni * 64 + lane;               // [0,256)
  const int cb   = q * 2;                        // cell base (row*64+dim)
  const uint32_t jn = (uint32_t)(r0g * 64 + cb);
  const int nrow = cb >> 6;
  const int ndim = cb & 63;
  float* nb_w = &nbuf[nrow * NBW + ndim];        // + buf*8*NBW at use

  // ---- GEMV state
  short8 wiH0, wiL0, wiH1, wiL1, woH0, woL0, woH1, woL1;
  float cp[4] = {0.f, 0.f, 0.f, 0.f}, xo[4] = {0.f, 0.f, 0.f, 0.f};
  float bo = 0.f, tp = 0.f;
  uint32_t j0 = 0;

  if (gemv) {
#pragma unroll
    for (int j = 0; j < 8; ++j) {
      short h, l;
      split_bf16(Win[(kq0 + j) * 64 + dim], h, l);  wiH0[j] = h; wiL0[j] = l;
      split_bf16(Win[(kq1 + j) * 64 + dim], h, l);  wiH1[j] = h; wiL1[j] = l;
      split_bf16(Wout[(kq0 + j) * 64 + dim], h, l); woH0[j] = h; woL0[j] = l;
      split_bf16(Wout[(kq1 + j) * 64 + dim], h, l); woH1[j] = h; woL1[j] = l;
    }
    bo = bout[dim];
    j0 = (uint32_t)((r0g + rowb) * 64 + dim);    // rowb clamped for !own
    if (own) {
#pragma unroll
      for (int r = 0; r < 4; ++r) cp[r] = cproj[j0 + r * 64u];
#pragma unroll
      for (int r = 0; r < 4; ++r) {
        xo[r] = jax_bits_to_normal(jax_random_bits32(0u, 1u, j0 + r * 64u));
        short h, l;
        split_bf16(xo[r], h, l);
        Xh[(rowb + r) * XLDW + dim] = h; Xl[(rowb + r) * XLDW + dim] = l;
      }
    }
    tp = tpb[199 * 64 + dim];
  } else {
    // prologue: noise for t=199 into nbuf[1]
    const uint32_t fk0 = su[199 * 8 + 5];
    const uint32_t fk1 = su[199 * 8 + 6];
    float* d = nb_w + 8 * NBW;                   // buf 1
    d[0] = jax_bits_to_normal(jax_random_bits32(fk0, fk1, jn + 0u));
    d[1] = jax_bits_to_normal(jax_random_bits32(fk0, fk1, jn + 1u));
  }
  __syncthreads();

#pragma unroll 1
  for (int t = 199; t >= 0; --t) {
    float sr = 0.f, srm1 = 0.f, c1 = 0.f, c2 = 0.f, sg = 0.f;
    float n[4], tpn = 0.f;
    f32x4 acc;
    uint32_t gk0 = 0, gk1 = 0;
    float* nd = nullptr;

    if (gemv) {
      sr   = sched[t * 8 + 0];
      srm1 = sched[t * 8 + 1];
      c1   = sched[t * 8 + 2];
      c2   = sched[t * 8 + 3];
      sg   = sched[t * 8 + 4];
      // noise for this step (produced >= one barrier-pair ago)
      const float* nr = &nbuf[(t & 1) * 8 * NBW + rowb * NBW + dim];
#pragma unroll
      for (int r = 0; r < 4; ++r) n[r] = nr[r * NBW];

      // ---- phase A: in-GEMV, full K=64
#pragma unroll
      for (int r = 0; r < 4; ++r) acc[r] = tp + cp[r];
      {
        short8 xh0 = ld_frag16(&Xh[arow * XLDW + kq0]);
        short8 xl0 = ld_frag16(&Xl[arow * XLDW + kq0]);
        short8 xh1 = ld_frag16(&Xh[arow * XLDW + kq1]);
        short8 xl1 = ld_frag16(&Xl[arow * XLDW + kq1]);
        acc = __builtin_amdgcn_mfma_f32_16x16x32_bf16(xl0, wiH0, acc, 0, 0, 0);
        acc = __builtin_amdgcn_mfma_f32_16x16x32_bf16(xh0, wiL0, acc, 0, 0, 0);
        acc = __builtin_amdgcn_mfma_f32_16x16x32_bf16(xh0, wiH0, acc, 0, 0, 0);
        acc = __builtin_amdgcn_mfma_f32_16x16x32_bf16(xl1, wiH1, acc, 0, 0, 0);
        acc = __builtin_amdgcn_mfma_f32_16x16x32_bf16(xh1, wiL1, acc, 0, 0, 0);
        acc = __builtin_amdgcn_mfma_f32_16x16x32_bf16(xh1, wiH1, acc, 0, 0, 0);
      }
      if (own) {
#pragma unroll
        for (int r = 0; r < 4; ++r) {
          float v = acc[r];
          v = v * __builtin_amdgcn_rcpf(1.0f + __expf(-v));
          short h, l;
          split_bf16(v, h, l);
          Hh[(rowb + r) * XLDW + dim] = h; Hl[(rowb + r) * XLDW + dim] = l;
        }
      }
      int tn = (t > 0) ? (t - 1) : 0;
      tpn = tpb[tn * 64 + dim];                  // prefetch next tp
    } else if (t > 0) {
      // noise for step t-1, first value
      gk0 = su[(t - 1) * 8 + 5];
      gk1 = su[(t - 1) * 8 + 6];
      nd = nb_w + ((t - 1) & 1) * 8 * NBW;
      nd[0] = jax_bits_to_normal(jax_random_bits32(gk0, gk1, jn + 0u));
    }
    __syncthreads();                              // B1

    if (gemv) {
      // ---- phase B: out-GEMV, full K=64, update 4 cells, restage X
      f32x4 eac;
#pragma unroll
      for (int r = 0; r < 4; ++r) eac[r] = bo;
      {
        short8 hh0 = ld_frag16(&Hh[arow * XLDW + kq0]);
        short8 hl0 = ld_frag16(&Hl[arow * XLDW + kq0]);
        short8 hh1 = ld_frag16(&Hh[arow * XLDW + kq1]);
        short8 hl1 = ld_frag16(&Hl[arow * XLDW + kq1]);
        eac = __builtin_amdgcn_mfma_f32_16x16x32_bf16(hl0, woH0, eac, 0, 0, 0);
        eac = __builtin_amdgcn_mfma_f32_16x16x32_bf16(hh0, woL0, eac, 0, 0, 0);
        eac = __builtin_amdgcn_mfma_f32_16x16x32_bf16(hh0, woH0, eac, 0, 0, 0);
        eac = __builtin_amdgcn_mfma_f32_16x16x32_bf16(hl1, woH1, eac, 0, 0, 0);
        eac = __builtin_amdgcn_mfma_f32_16x16x32_bf16(hh1, woL1, eac, 0, 0, 0);
        eac = __builtin_amdgcn_mfma_f32_16x16x32_bf16(hh1, woH1, eac, 0, 0, 0);
      }
      if (own) {
#pragma unroll
        for (int r = 0; r < 4; ++r) {
          float xc = fminf(1.f, fmaxf(-1.f, sr * xo[r] - srm1 * eac[r]));
          xo[r] = c1 * xc + c2 * xo[r] + sg * n[r];
          short h, l;
          split_bf16(xo[r], h, l);
          Xh[(rowb + r) * XLDW + dim] = h; Xl[(rowb + r) * XLDW + dim] = l;
        }
      }
      tp = tpn;
    } else if (t > 0) {
      // noise for step t-1, second value
      nd[1] = jax_bits_to_normal(jax_random_bits32(gk0, gk1, jn + 1u));
    }
    __syncthreads();                              // B2
  }

  if (gemv && own) {
#pragma unroll
    for (int r = 0; r < 4; ++r) out[j0 + r * 64u] = xo[r];
  }
}

// ---------------------------------------------------------------------------
extern "C" void kernel_launch(void* const* d_in, const int* in_sizes, int n_in,
                              void* d_out, int out_size, void* d_ws, size_t ws_size,
                              hipStream_t stream)
{
  const int*   seq  = (const int*)  d_in[0];
  const float* emb  = (const float*)d_in[1];
  const float* W1   = (const float*)d_in[2];
  const float* b1   = (const float*)d_in[3];
  const float* W2   = (const float*)d_in[4];
  const float* b2   = (const float*)d_in[5];
  const float* Win  = (const float*)d_in[6];
  const float* bin  = (const float*)d_in[7];
  const float* Wt   = (const float*)d_in[8];
  const float* bt   = (const float*)d_in[9];
  const float* Wc   = (const float*)d_in[10];
  const float* bc   = (const float*)d_in[11];
  const float* Wout = (const float*)d_in[12];
  const float* bout = (const float*)d_in[13];

  float* out   = (float*)d_out;
  float* ws    = (float*)d_ws;
  float* cproj = ws;                       // 524288 floats
  float* tpb   = ws + 524288;              // 12800 floats
  float* sched = ws + 524288 + 12800;      // 1600 floats (t*8 layout)
  float* pooled = out;                     // reuse d_out as scratch

  k_pool <<<2048, 256, 0, stream>>>(seq, emb, pooled);
  k_enc  <<<1024, 256, 0, stream>>>(pooled, W1, b1, W2, b2, Wc, bc, cproj);
  k_prep <<<200, 64, 0, stream>>>(Wt, bt, bin, tpb, sched);
  k_ddpm <<<1024, 512, 0, stream>>>(Win, Wout, bout, cproj, tpb, sched, out);
}

// Round 11
// 530.288 us; speedup vs baseline: 1.4996x; 1.2315x over previous
//
#include <hip/hip_runtime.h>
#include <cstdint>

// ---------------------------------------------------------------------------
// DDPM + VAE query encoder, MI355X round 23.
// r22 post-mortem: spills fixed but occupancy pinned at 4 waves/SIMD -- the
// CSV VGPR_Count hides the AGPR side of the unified file; total ~104-128 regs
// -> 4 waves/SIMD is this structure's register ceiling. Stop chasing 8.
// r20 re-model: issue-bound with ROLE IMBALANCE -- noise waves issue ~1570
// cy/step (4 draws), GEMV waves ~450; lockstep barriers stretch every
// segment to the slower class. Fix: homogenize. ALL 8 waves draw exactly 2
// noise values/lane/step (1 per segment) into nbuf (producer cells
// cb = w*128+lane*2, bijective over the block's 1024 cells); GEMV waves do
// GEMV + 1 draw per segment. Per-SIMD issue ~2900 cy/step (was ~4100).
// Consumers and threefry bits unchanged -> bit-exact.
// Base: r20 (512x512, 16 rows/block, weights in regs, 2 barriers/step).
// ---------------------------------------------------------------------------

#define DEVI __device__ __forceinline__

typedef __attribute__((ext_vector_type(8))) short short8;
typedef __attribute__((ext_vector_type(4))) float f32x4;

DEVI void threefry2x32(uint32_t k0, uint32_t k1, uint32_t x0, uint32_t x1,
                       uint32_t &o0, uint32_t &o1)
{
  const uint32_t ks2 = k0 ^ k1 ^ 0x1BD11BDAu;
  x0 += k0; x1 += k1;
#define TFR(r) { x0 += x1; x1 = __builtin_rotateleft32(x1, r); x1 ^= x0; }
  TFR(13u) TFR(15u) TFR(26u) TFR(6u)   x0 += k1;  x1 += ks2 + 1u;
  TFR(17u) TFR(29u) TFR(16u) TFR(24u)  x0 += ks2; x1 += k0 + 2u;
  TFR(13u) TFR(15u) TFR(26u) TFR(6u)   x0 += k0;  x1 += k1 + 3u;
  TFR(17u) TFR(29u) TFR(16u) TFR(24u)  x0 += k1;  x1 += ks2 + 4u;
  TFR(13u) TFR(15u) TFR(26u) TFR(6u)   x0 += ks2; x1 += k0 + 5u;
#undef TFR
  o0 = x0; o1 = x1;
}

DEVI uint32_t jax_random_bits32(uint32_t k0, uint32_t k1, uint32_t j)
{
  uint32_t a, b;
  threefry2x32(k0, k1, 0u, j, a, b);
  return a ^ b;
}

DEVI float jax_bits_to_normal(uint32_t bits)
{
  const float LO = -0.99999994f;
  float f = __uint_as_float((bits >> 9) | 0x3f800000u) - 1.0f;
  float u = fmaxf(LO, f * 2.0f + LO);
  float w = -__logf((1.0f - u) * (1.0f + u));
  float p;
  if (w < 5.0f) {
    w = w - 2.5f;
    p =              2.81022636e-08f;
    p = fmaf(p, w,   3.43273939e-07f);
    p = fmaf(p, w,  -3.5233877e-06f);
    p = fmaf(p, w,  -4.39150654e-06f);
    p = fmaf(p, w,   0.00021858087f);
    p = fmaf(p, w,  -0.00125372503f);
    p = fmaf(p, w,  -0.00417768164f);
    p = fmaf(p, w,   0.246640727f);
    p = fmaf(p, w,   1.50140941f);
  } else {
    w = sqrtf(w) - 3.0f;
    p =             -0.000200214257f;
    p = fmaf(p, w,   0.000100950558f);
    p = fmaf(p, w,   0.00134934322f);
    p = fmaf(p, w,  -0.00367342844f);
    p = fmaf(p, w,   0.00573950773f);
    p = fmaf(p, w,  -0.0076224613f);
    p = fmaf(p, w,   0.00943887047f);
    p = fmaf(p, w,   1.00167406f);
    p = fmaf(p, w,   2.83297682f);
  }
  return 1.41421356237f * (p * u);
}

DEVI short bf16_hi_trunc(float x) { return (short)(__float_as_uint(x) >> 16); }
DEVI float bf16_to_f32(short h)
{
  return __uint_as_float(((uint32_t)(unsigned short)h) << 16);
}
DEVI void split_bf16(float x, short &h, short &l)
{
  h = bf16_hi_trunc(x);
  float r = x - bf16_to_f32(h);
  l = bf16_hi_trunc(r);
}

// 8-short fragment from 16B-aligned LDS (stride-72 rows): one b128 read.
DEVI short8 ld_frag16(const short* p)
{
  union { int4 v; short8 s; } u;
  u.v = *(const int4*)p;
  return u.s;
}

// ---------------------------------------------------------------------------
__global__ __launch_bounds__(256)
void k_pool(const int* __restrict__ seq, const float* __restrict__ emb,
            float* __restrict__ pooled)
{
  const int lane = threadIdx.x & 63;
  const int r    = blockIdx.x * 4 + (threadIdx.x >> 6);
  const int* row = seq + r * 100;
  float s = 0.f;
  int cnt = 0;
  for (int l = 0; l < 100; ++l) {
    int id = row[l];
    cnt += (id != 0);
    s += emb[id * 64 + lane];
  }
  pooled[r * 64 + lane] = s / sqrtf((float)cnt);
}

// ---------------------------------------------------------------------------
__global__ __launch_bounds__(256)
void k_enc(const float* __restrict__ pooled,
           const float* __restrict__ W1, const float* __restrict__ b1,
           const float* __restrict__ W2, const float* __restrict__ b2,
           const float* __restrict__ Wc, const float* __restrict__ bc,
           float* __restrict__ cproj)
{
  __shared__ float p_s[8][64];
  __shared__ float h_s[8][256];
  __shared__ float mu_s[8][64];
  const int tid = threadIdx.x;
  const int r0  = blockIdx.x * 8;

  for (int i = tid; i < 8 * 64; i += 256)
    p_s[i >> 6][i & 63] = pooled[r0 * 64 + i];
  __syncthreads();

  float hacc[8];
#pragma unroll
  for (int r = 0; r < 8; ++r) hacc[r] = b1[tid];
  for (int k = 0; k < 64; ++k) {
    float w = W1[k * 256 + tid];
#pragma unroll
    for (int r = 0; r < 8; ++r) hacc[r] = fmaf(p_s[r][k], w, hacc[r]);
  }
#pragma unroll
  for (int r = 0; r < 8; ++r) h_s[r][tid] = fmaxf(hacc[r], 0.f);
  __syncthreads();

#pragma unroll
  for (int pass = 0; pass < 2; ++pass) {
    int r = pass * 4 + (tid >> 6);
    int j = tid & 63;
    float acc = b2[j];
    for (int k = 0; k < 256; ++k)
      acc = fmaf(h_s[r][k], W2[k * 128 + j], acc);
    mu_s[r][j] = acc;
  }
  __syncthreads();

#pragma unroll
  for (int pass = 0; pass < 2; ++pass) {
    int r = pass * 4 + (tid >> 6);
    int j = tid & 63;
    float acc = bc[j];
    for (int k = 0; k < 64; ++k)
      acc = fmaf(mu_s[r][k], Wc[k * 64 + j], acc);
    cproj[(r0 + r) * 64 + j] = acc;
  }
}

// ---------------------------------------------------------------------------
// k_prep: 200 blocks x 64 threads. Block t computes sched[t*8+..] AND
// tpb[t][d] = temb(t)@W_t + b_t + b_in.
__global__ __launch_bounds__(64)
void k_prep(const float* __restrict__ Wt, const float* __restrict__ bt,
            const float* __restrict__ bin, float* __restrict__ tpb,
            float* __restrict__ sched)
{
  __shared__ float temb[64];
  const int t = blockIdx.x;
  const int d = threadIdx.x;
  const float lg = logf(10000.0f);
  {
    int i = d & 31;
    float fr  = expf((-lg * (float)i) / 32.0f);
    float ang = (float)t * fr;
    temb[d] = (d < 32) ? cosf(ang) : sinf(ang);
  }
  if (d == 0) {
    const float start = (float)(5.0 * 1e-4);
    const float stop  = (float)(5.0 * 0.02);
    const float delta = stop - start;
    float prod = 1.f, acp_prev = 1.f, beta = 0.f, alpha = 1.f;
    for (int i = 0; i <= t; ++i) {
      beta  = start + ((float)i * delta) / 199.0f;
      alpha = 1.0f - beta;
      acp_prev = prod;
      prod = prod * alpha;
    }
    float acp = prod;
    float om  = 1.0f - acp;
    sched[t * 8 + 0] = sqrtf(1.0f / acp);
    sched[t * 8 + 1] = sqrtf(1.0f / acp - 1.0f);
    sched[t * 8 + 2] = beta * sqrtf(acp_prev) / om;
    sched[t * 8 + 3] = (1.0f - acp_prev) * sqrtf(alpha) / om;
    float pv = beta * (1.0f - acp_prev) / om;
    sched[t * 8 + 4] = (t > 0) ? sqrtf(pv) : 0.0f;
    uint32_t fk0, fk1;
    threefry2x32(0u, 2u, 0u, (uint32_t)t, fk0, fk1);
    ((uint32_t*)sched)[t * 8 + 5] = fk0;
    ((uint32_t*)sched)[t * 8 + 6] = fk1;
  }
  __syncthreads();
  float acc = bt[d] + bin[d];
  for (int k = 0; k < 64; ++k)
    acc = fmaf(temb[k], Wt[k * 64 + d], acc);
  tpb[t * 64 + d] = acc;
}

// ---------------------------------------------------------------------------
// K_ddpm: 512 blocks x 512 threads (8 waves). Block owns 16 rows.
// Waves 0-3 (GEMV): wave nt owns cols 16nt..16nt+15; lane (quad,nn) owns
//   rows quad*4..+3 at col dim. Full-K GEMV, 6 MFMA/phase, weights in regs.
// ALL 8 waves: 2 noise draws/lane/step (1 per segment) into nbuf[(t-1)&1],
//   producer cells cb = w*128 + lane*2 (bijective over 1024 block cells).
#define XLDW  72   // X/H row stride (shorts); 144 B -> 16B-aligned frags
#define NBW   68   // nbuf row stride (floats)

__global__
__attribute__((amdgpu_flat_work_group_size(512, 512), amdgpu_waves_per_eu(4, 4)))
void k_ddpm(const float* __restrict__ Win, const float* __restrict__ Wout,
            const float* __restrict__ bout,
            const float* __restrict__ cproj, const float* __restrict__ tpb,
            const float* __restrict__ sched, float* __restrict__ out)
{
  __shared__ __align__(16) short Xh[16 * XLDW], Xl[16 * XLDW];
  __shared__ __align__(16) short Hh[16 * XLDW], Hl[16 * XLDW];
  __shared__ __align__(16) float nbuf[2 * 16 * NBW];
  // total: 4*2304 + 8704 = 17920 B

  const int tid  = threadIdx.x;
  const int lane = tid & 63;
  const int w    = tid >> 6;
  const bool gemv = (w < 4);
  const int r0g  = blockIdx.x * 16;
  const uint32_t* su = (const uint32_t*)sched;

  // ---- GEMV-wave ids
  const int nt   = w & 3;
  const int nn   = lane & 15;
  const int quad = lane >> 4;
  const int dim  = nt * 16 + nn;
  const int arow = nn;
  const int kq0  = quad * 8;
  const int kq1  = 32 + quad * 8;
  const int rowb = quad * 4;                       // owned rows rowb..rowb+3

  // ---- producer ids (ALL waves): 2 consecutive cells
  const int cb   = w * 128 + lane * 2;             // cell base (row*64+dim)
  const uint32_t jn = (uint32_t)(r0g * 64 + cb);   // global noise index base
  const int nrow = cb >> 6;
  const int ndim = cb & 63;
  float* nb_w = &nbuf[nrow * NBW + ndim];          // + buf*16*NBW at use

  // ---- GEMV state
  short8 wiH0, wiL0, wiH1, wiL1, woH0, woL0, woH1, woL1;
  float cp[4] = {0.f, 0.f, 0.f, 0.f}, xo[4] = {0.f, 0.f, 0.f, 0.f};
  float bo = 0.f, tp = 0.f;
  uint32_t j0 = 0;

  if (gemv) {
#pragma unroll
    for (int j = 0; j < 8; ++j) {
      short h, l;
      split_bf16(Win[(kq0 + j) * 64 + dim], h, l);  wiH0[j] = h; wiL0[j] = l;
      split_bf16(Win[(kq1 + j) * 64 + dim], h, l);  wiH1[j] = h; wiL1[j] = l;
      split_bf16(Wout[(kq0 + j) * 64 + dim], h, l); woH0[j] = h; woL0[j] = l;
      split_bf16(Wout[(kq1 + j) * 64 + dim], h, l); woH1[j] = h; woL1[j] = l;
    }
    bo = bout[dim];
    j0 = (uint32_t)((r0g + rowb) * 64 + dim);
#pragma unroll
    for (int r = 0; r < 4; ++r) cp[r] = cproj[j0 + r * 64u];
#pragma unroll
    for (int r = 0; r < 4; ++r) {
      xo[r] = jax_bits_to_normal(jax_random_bits32(0u, 1u, j0 + r * 64u));
      short h, l;
      split_bf16(xo[r], h, l);
      Xh[(rowb + r) * XLDW + dim] = h; Xl[(rowb + r) * XLDW + dim] = l;
    }
    tp = tpb[199 * 64 + dim];
  }
  // prologue noise for t=199 into nbuf[1]: ALL waves, 2 cells each
  {
    const uint32_t fk0 = su[199 * 8 + 5];
    const uint32_t fk1 = su[199 * 8 + 6];
    float* d = nb_w + 16 * NBW;                    // buf 1
    d[0] = jax_bits_to_normal(jax_random_bits32(fk0, fk1, jn + 0u));
    d[1] = jax_bits_to_normal(jax_random_bits32(fk0, fk1, jn + 1u));
  }
  __syncthreads();

#pragma unroll 1
  for (int t = 199; t >= 0; --t) {
    // uniform draw setup for step t-1 (carried across B1 in regs)
    uint32_t gk0 = 0, gk1 = 0;
    float* nd = nullptr;
    if (t > 0) {
      gk0 = su[(t - 1) * 8 + 5];
      gk1 = su[(t - 1) * 8 + 6];
      nd = nb_w + ((t - 1) & 1) * 16 * NBW;
    }

    float sr = 0.f, srm1 = 0.f, c1 = 0.f, c2 = 0.f, sg = 0.f, tpn = 0.f;
    f32x4 acc;

    if (gemv) {
      sr   = sched[t * 8 + 0];
      srm1 = sched[t * 8 + 1];
      c1   = sched[t * 8 + 2];
      c2   = sched[t * 8 + 3];
      sg   = sched[t * 8 + 4];

      // ---- phase A: in-GEMV, full K=64, bias in all 4 owned slots
#pragma unroll
      for (int r = 0; r < 4; ++r) acc[r] = tp + cp[r];
      {
        short8 xh0 = ld_frag16(&Xh[arow * XLDW + kq0]);
        short8 xl0 = ld_frag16(&Xl[arow * XLDW + kq0]);
        short8 xh1 = ld_frag16(&Xh[arow * XLDW + kq1]);
        short8 xl1 = ld_frag16(&Xl[arow * XLDW + kq1]);
        acc = __builtin_amdgcn_mfma_f32_16x16x32_bf16(xl0, wiH0, acc, 0, 0, 0);
        acc = __builtin_amdgcn_mfma_f32_16x16x32_bf16(xh0, wiL0, acc, 0, 0, 0);
        acc = __builtin_amdgcn_mfma_f32_16x16x32_bf16(xh0, wiH0, acc, 0, 0, 0);
        acc = __builtin_amdgcn_mfma_f32_16x16x32_bf16(xl1, wiH1, acc, 0, 0, 0);
        acc = __builtin_amdgcn_mfma_f32_16x16x32_bf16(xh1, wiL1, acc, 0, 0, 0);
        acc = __builtin_amdgcn_mfma_f32_16x16x32_bf16(xh1, wiH1, acc, 0, 0, 0);
      }
#pragma unroll
      for (int r = 0; r < 4; ++r) {
        float v = acc[r];
        v = v * __builtin_amdgcn_rcpf(1.0f + __expf(-v));
        short h, l;
        split_bf16(v, h, l);
        Hh[(rowb + r) * XLDW + dim] = h; Hl[(rowb + r) * XLDW + dim] = l;
      }
      int tn = (t > 0) ? (t - 1) : 0;
      tpn = tpb[tn * 64 + dim];                    // prefetch next tp
    }
    // uniform: first draw for step t-1 (all 8 waves)
    if (t > 0)
      nd[0] = jax_bits_to_normal(jax_random_bits32(gk0, gk1, jn + 0u));
    __syncthreads();                                // B1

    if (gemv) {
      // noise for this step (buf t&1 last written iter t+1 before B2)
      float n[4];
      const float* nr = &nbuf[(t & 1) * 16 * NBW + rowb * NBW + dim];
#pragma unroll
      for (int r = 0; r < 4; ++r) n[r] = nr[r * NBW];

      // ---- phase B: out-GEMV, full K=64, update 4 cells, restage X
      f32x4 eac;
#pragma unroll
      for (int r = 0; r < 4; ++r) eac[r] = bo;
      {
        short8 hh0 = ld_frag16(&Hh[arow * XLDW + kq0]);
        short8 hl0 = ld_frag16(&Hl[arow * XLDW + kq0]);
        short8 hh1 = ld_frag16(&Hh[arow * XLDW + kq1]);
        short8 hl1 = ld_frag16(&Hl[arow * XLDW + kq1]);
        eac = __builtin_amdgcn_mfma_f32_16x16x32_bf16(hl0, woH0, eac, 0, 0, 0);
        eac = __builtin_amdgcn_mfma_f32_16x16x32_bf16(hh0, woL0, eac, 0, 0, 0);
        eac = __builtin_amdgcn_mfma_f32_16x16x32_bf16(hh0, woH0, eac, 0, 0, 0);
        eac = __builtin_amdgcn_mfma_f32_16x16x32_bf16(hl1, woH1, eac, 0, 0, 0);
        eac = __builtin_amdgcn_mfma_f32_16x16x32_bf16(hh1, woL1, eac, 0, 0, 0);
        eac = __builtin_amdgcn_mfma_f32_16x16x32_bf16(hh1, woH1, eac, 0, 0, 0);
      }
#pragma unroll
      for (int r = 0; r < 4; ++r) {
        float xc = fminf(1.f, fmaxf(-1.f, sr * xo[r] - srm1 * eac[r]));
        xo[r] = c1 * xc + c2 * xo[r] + sg * n[r];
        short h, l;
        split_bf16(xo[r], h, l);
        Xh[(rowb + r) * XLDW + dim] = h; Xl[(rowb + r) * XLDW + dim] = l;
      }
      tp = tpn;
    }
    // uniform: second draw for step t-1 (all 8 waves)
    if (t > 0)
      nd[1] = jax_bits_to_normal(jax_random_bits32(gk0, gk1, jn + 1u));
    __syncthreads();                                // B2
  }

  if (gemv) {
#pragma unroll
    for (int r = 0; r < 4; ++r) out[j0 + r * 64u] = xo[r];
  }
}

// ---------------------------------------------------------------------------
extern "C" void kernel_launch(void* const* d_in, const int* in_sizes, int n_in,
                              void* d_out, int out_size, void* d_ws, size_t ws_size,
                              hipStream_t stream)
{
  const int*   seq  = (const int*)  d_in[0];
  const float* emb  = (const float*)d_in[1];
  const float* W1   = (const float*)d_in[2];
  const float* b1   = (const float*)d_in[3];
  const float* W2   = (const float*)d_in[4];
  const float* b2   = (const float*)d_in[5];
  const float* Win  = (const float*)d_in[6];
  const float* bin  = (const float*)d_in[7];
  const float* Wt   = (const float*)d_in[8];
  const float* bt   = (const float*)d_in[9];
  const float* Wc   = (const float*)d_in[10];
  const float* bc   = (const float*)d_in[11];
  const float* Wout = (const float*)d_in[12];
  const float* bout = (const float*)d_in[13];

  float* out   = (float*)d_out;
  float* ws    = (float*)d_ws;
  float* cproj = ws;                       // 524288 floats
  float* tpb   = ws + 524288;              // 12800 floats
  float* sched = ws + 524288 + 12800;      // 1600 floats (t*8 layout)
  float* pooled = out;                     // reuse d_out as scratch

  k_pool <<<2048, 256, 0, stream>>>(seq, emb, pooled);
  k_enc  <<<1024, 256, 0, stream>>>(pooled, W1, b1, W2, b2, Wc, bc, cproj);
  k_prep <<<200, 64, 0, stream>>>(Wt, bt, bin, tpb, sched);
  k_ddpm <<<512, 512, 0, stream>>>(Win, Wout, bout, cproj, tpb, sched, out);
}

// Round 12
// 523.700 us; speedup vs baseline: 1.5185x; 1.0126x over previous
//
#include <hip/hip_runtime.h>
#include <cstdint>

// ---------------------------------------------------------------------------
// DDPM + VAE query encoder, MI355X round 24.
// r23 post-mortem: homogenized draws -> 428 us; VALUBusy 94.7 = any-of-4 ->
// per-SIMD issue ~52%: HALF the cycles nothing can issue. Cause: 4 waves/SIMD
// (register ceiling) x 1 serial draw chain per wave per segment (~500 cy
// dependent threefry+erfinv, ~200 cy issue) = only 4 chains to fill latency.
// r19's k_noise proved 4-chain ILP packs to 388 cy/wave-draw.
// r24: software-pipeline the draw across segments -- segA runs BOTH threefry
// chains (bits only, ILP-2, ~180 cy serial each), segB runs BOTH erfinv
// chains (ILP-2). 8 chains/SIMD per segment, half the serial length. Same
// bits, same order -> bit-exact. +2 VGPR carried across B1 (52 -> ~58).
// Also: k_prep fused into k_pool as block-range split (one fewer dispatch).
// ---------------------------------------------------------------------------

#define DEVI __device__ __forceinline__

typedef __attribute__((ext_vector_type(8))) short short8;
typedef __attribute__((ext_vector_type(4))) float f32x4;

DEVI void threefry2x32(uint32_t k0, uint32_t k1, uint32_t x0, uint32_t x1,
                       uint32_t &o0, uint32_t &o1)
{
  const uint32_t ks2 = k0 ^ k1 ^ 0x1BD11BDAu;
  x0 += k0; x1 += k1;
#define TFR(r) { x0 += x1; x1 = __builtin_rotateleft32(x1, r); x1 ^= x0; }
  TFR(13u) TFR(15u) TFR(26u) TFR(6u)   x0 += k1;  x1 += ks2 + 1u;
  TFR(17u) TFR(29u) TFR(16u) TFR(24u)  x0 += ks2; x1 += k0 + 2u;
  TFR(13u) TFR(15u) TFR(26u) TFR(6u)   x0 += k0;  x1 += k1 + 3u;
  TFR(17u) TFR(29u) TFR(16u) TFR(24u)  x0 += k1;  x1 += ks2 + 4u;
  TFR(13u) TFR(15u) TFR(26u) TFR(6u)   x0 += ks2; x1 += k0 + 5u;
#undef TFR
  o0 = x0; o1 = x1;
}

DEVI uint32_t jax_random_bits32(uint32_t k0, uint32_t k1, uint32_t j)
{
  uint32_t a, b;
  threefry2x32(k0, k1, 0u, j, a, b);
  return a ^ b;
}

DEVI float jax_bits_to_normal(uint32_t bits)
{
  const float LO = -0.99999994f;
  float f = __uint_as_float((bits >> 9) | 0x3f800000u) - 1.0f;
  float u = fmaxf(LO, f * 2.0f + LO);
  float w = -__logf((1.0f - u) * (1.0f + u));
  float p;
  if (w < 5.0f) {
    w = w - 2.5f;
    p =              2.81022636e-08f;
    p = fmaf(p, w,   3.43273939e-07f);
    p = fmaf(p, w,  -3.5233877e-06f);
    p = fmaf(p, w,  -4.39150654e-06f);
    p = fmaf(p, w,   0.00021858087f);
    p = fmaf(p, w,  -0.00125372503f);
    p = fmaf(p, w,  -0.00417768164f);
    p = fmaf(p, w,   0.246640727f);
    p = fmaf(p, w,   1.50140941f);
  } else {
    w = sqrtf(w) - 3.0f;
    p =             -0.000200214257f;
    p = fmaf(p, w,   0.000100950558f);
    p = fmaf(p, w,   0.00134934322f);
    p = fmaf(p, w,  -0.00367342844f);
    p = fmaf(p, w,   0.00573950773f);
    p = fmaf(p, w,  -0.0076224613f);
    p = fmaf(p, w,   0.00943887047f);
    p = fmaf(p, w,   1.00167406f);
    p = fmaf(p, w,   2.83297682f);
  }
  return 1.41421356237f * (p * u);
}

DEVI short bf16_hi_trunc(float x) { return (short)(__float_as_uint(x) >> 16); }
DEVI float bf16_to_f32(short h)
{
  return __uint_as_float(((uint32_t)(unsigned short)h) << 16);
}
DEVI void split_bf16(float x, short &h, short &l)
{
  h = bf16_hi_trunc(x);
  float r = x - bf16_to_f32(h);
  l = bf16_hi_trunc(r);
}

// 8-short fragment from 16B-aligned LDS (stride-72 rows): one b128 read.
DEVI short8 ld_frag16(const short* p)
{
  union { int4 v; short8 s; } u;
  u.v = *(const int4*)p;
  return u.s;
}

// ---------------------------------------------------------------------------
// k_poolprep: blocks [0,2048) = pool (4 rows each, r23 k_pool verbatim);
// blocks [2048,2248) = prep for t = blockIdx-2048 (r23 k_prep, 64 of 256
// threads active). Independent inputs; prep hides under the pool gather.
__global__ __launch_bounds__(256)
void k_poolprep(const int* __restrict__ seq, const float* __restrict__ emb,
                float* __restrict__ pooled,
                const float* __restrict__ Wt, const float* __restrict__ bt,
                const float* __restrict__ bin, float* __restrict__ tpb,
                float* __restrict__ sched)
{
  if (blockIdx.x < 2048u) {
    const int lane = threadIdx.x & 63;
    const int r    = blockIdx.x * 4 + (threadIdx.x >> 6);
    const int* row = seq + r * 100;
    float s = 0.f;
    int cnt = 0;
    for (int l = 0; l < 100; ++l) {
      int id = row[l];
      cnt += (id != 0);
      s += emb[id * 64 + lane];
    }
    pooled[r * 64 + lane] = s / sqrtf((float)cnt);
  } else {
    __shared__ float temb[64];
    const int t = blockIdx.x - 2048;
    const int d = threadIdx.x;
    if (d < 64) {
      const float lg = logf(10000.0f);
      int i = d & 31;
      float fr  = expf((-lg * (float)i) / 32.0f);
      float ang = (float)t * fr;
      temb[d] = (d < 32) ? cosf(ang) : sinf(ang);
      if (d == 0) {
        const float start = (float)(5.0 * 1e-4);
        const float stop  = (float)(5.0 * 0.02);
        const float delta = stop - start;
        float prod = 1.f, acp_prev = 1.f, beta = 0.f, alpha = 1.f;
        for (int i2 = 0; i2 <= t; ++i2) {
          beta  = start + ((float)i2 * delta) / 199.0f;
          alpha = 1.0f - beta;
          acp_prev = prod;
          prod = prod * alpha;
        }
        float acp = prod;
        float om  = 1.0f - acp;
        sched[t * 8 + 0] = sqrtf(1.0f / acp);
        sched[t * 8 + 1] = sqrtf(1.0f / acp - 1.0f);
        sched[t * 8 + 2] = beta * sqrtf(acp_prev) / om;
        sched[t * 8 + 3] = (1.0f - acp_prev) * sqrtf(alpha) / om;
        float pv = beta * (1.0f - acp_prev) / om;
        sched[t * 8 + 4] = (t > 0) ? sqrtf(pv) : 0.0f;
        uint32_t fk0, fk1;
        threefry2x32(0u, 2u, 0u, (uint32_t)t, fk0, fk1);
        ((uint32_t*)sched)[t * 8 + 5] = fk0;
        ((uint32_t*)sched)[t * 8 + 6] = fk1;
      }
    }
    __syncthreads();
    if (d < 64) {
      float acc = bt[d] + bin[d];
      for (int k = 0; k < 64; ++k)
        acc = fmaf(temb[k], Wt[k * 64 + d], acc);
      tpb[t * 64 + d] = acc;
    }
  }
}

// ---------------------------------------------------------------------------
__global__ __launch_bounds__(256)
void k_enc(const float* __restrict__ pooled,
           const float* __restrict__ W1, const float* __restrict__ b1,
           const float* __restrict__ W2, const float* __restrict__ b2,
           const float* __restrict__ Wc, const float* __restrict__ bc,
           float* __restrict__ cproj)
{
  __shared__ float p_s[8][64];
  __shared__ float h_s[8][256];
  __shared__ float mu_s[8][64];
  const int tid = threadIdx.x;
  const int r0  = blockIdx.x * 8;

  for (int i = tid; i < 8 * 64; i += 256)
    p_s[i >> 6][i & 63] = pooled[r0 * 64 + i];
  __syncthreads();

  float hacc[8];
#pragma unroll
  for (int r = 0; r < 8; ++r) hacc[r] = b1[tid];
  for (int k = 0; k < 64; ++k) {
    float w = W1[k * 256 + tid];
#pragma unroll
    for (int r = 0; r < 8; ++r) hacc[r] = fmaf(p_s[r][k], w, hacc[r]);
  }
#pragma unroll
  for (int r = 0; r < 8; ++r) h_s[r][tid] = fmaxf(hacc[r], 0.f);
  __syncthreads();

#pragma unroll
  for (int pass = 0; pass < 2; ++pass) {
    int r = pass * 4 + (tid >> 6);
    int j = tid & 63;
    float acc = b2[j];
    for (int k = 0; k < 256; ++k)
      acc = fmaf(h_s[r][k], W2[k * 128 + j], acc);
    mu_s[r][j] = acc;
  }
  __syncthreads();

#pragma unroll
  for (int pass = 0; pass < 2; ++pass) {
    int r = pass * 4 + (tid >> 6);
    int j = tid & 63;
    float acc = bc[j];
    for (int k = 0; k < 64; ++k)
      acc = fmaf(mu_s[r][k], Wc[k * 64 + j], acc);
    cproj[(r0 + r) * 64 + j] = acc;
  }
}

// ---------------------------------------------------------------------------
// K_ddpm: 512 blocks x 512 threads (8 waves). Block owns 16 rows.
// Waves 0-3 (GEMV): wave nt owns cols 16nt..16nt+15; lane (quad,nn) owns
//   rows quad*4..+3 at col dim. Full-K GEMV, 6 MFMA/phase, weights in regs.
// ALL 8 waves produce 2 noise values/lane/step, PIPELINED: segA = both
//   threefry chains (bits, ILP-2), segB = both erfinv chains + nbuf write.
//   Producer cells cb = w*128 + lane*2 (bijective over 1024 block cells).
#define XLDW  72   // X/H row stride (shorts); 144 B -> 16B-aligned frags
#define NBW   68   // nbuf row stride (floats)

__global__
__attribute__((amdgpu_flat_work_group_size(512, 512), amdgpu_waves_per_eu(4, 4)))
void k_ddpm(const float* __restrict__ Win, const float* __restrict__ Wout,
            const float* __restrict__ bout,
            const float* __restrict__ cproj, const float* __restrict__ tpb,
            const float* __restrict__ sched, float* __restrict__ out)
{
  __shared__ __align__(16) short Xh[16 * XLDW], Xl[16 * XLDW];
  __shared__ __align__(16) short Hh[16 * XLDW], Hl[16 * XLDW];
  __shared__ __align__(16) float nbuf[2 * 16 * NBW];
  // total: 4*2304 + 8704 = 17920 B

  const int tid  = threadIdx.x;
  const int lane = tid & 63;
  const int w    = tid >> 6;
  const bool gemv = (w < 4);
  const int r0g  = blockIdx.x * 16;
  const uint32_t* su = (const uint32_t*)sched;

  // ---- GEMV-wave ids
  const int nt   = w & 3;
  const int nn   = lane & 15;
  const int quad = lane >> 4;
  const int dim  = nt * 16 + nn;
  const int arow = nn;
  const int kq0  = quad * 8;
  const int kq1  = 32 + quad * 8;
  const int rowb = quad * 4;                       // owned rows rowb..rowb+3

  // ---- producer ids (ALL waves): 2 consecutive cells
  const int cb   = w * 128 + lane * 2;             // cell base (row*64+dim)
  const uint32_t jn = (uint32_t)(r0g * 64 + cb);   // global noise index base
  const int nrow = cb >> 6;
  const int ndim = cb & 63;
  float* nb_w = &nbuf[nrow * NBW + ndim];          // + buf*16*NBW at use

  // ---- GEMV state
  short8 wiH0, wiL0, wiH1, wiL1, woH0, woL0, woH1, woL1;
  float cp[4] = {0.f, 0.f, 0.f, 0.f}, xo[4] = {0.f, 0.f, 0.f, 0.f};
  float bo = 0.f, tp = 0.f;
  uint32_t j0 = 0;

  if (gemv) {
#pragma unroll
    for (int j = 0; j < 8; ++j) {
      short h, l;
      split_bf16(Win[(kq0 + j) * 64 + dim], h, l);  wiH0[j] = h; wiL0[j] = l;
      split_bf16(Win[(kq1 + j) * 64 + dim], h, l);  wiH1[j] = h; wiL1[j] = l;
      split_bf16(Wout[(kq0 + j) * 64 + dim], h, l); woH0[j] = h; woL0[j] = l;
      split_bf16(Wout[(kq1 + j) * 64 + dim], h, l); woH1[j] = h; woL1[j] = l;
    }
    bo = bout[dim];
    j0 = (uint32_t)((r0g + rowb) * 64 + dim);
#pragma unroll
    for (int r = 0; r < 4; ++r) cp[r] = cproj[j0 + r * 64u];
#pragma unroll
    for (int r = 0; r < 4; ++r) {
      xo[r] = jax_bits_to_normal(jax_random_bits32(0u, 1u, j0 + r * 64u));
      short h, l;
      split_bf16(xo[r], h, l);
      Xh[(rowb + r) * XLDW + dim] = h; Xl[(rowb + r) * XLDW + dim] = l;
    }
    tp = tpb[199 * 64 + dim];
  }
  // prologue noise for t=199 into nbuf[1]: ALL waves, 2 cells each
  {
    const uint32_t fk0 = su[199 * 8 + 5];
    const uint32_t fk1 = su[199 * 8 + 6];
    float* d = nb_w + 16 * NBW;                    // buf 1
    d[0] = jax_bits_to_normal(jax_random_bits32(fk0, fk1, jn + 0u));
    d[1] = jax_bits_to_normal(jax_random_bits32(fk0, fk1, jn + 1u));
  }
  __syncthreads();

#pragma unroll 1
  for (int t = 199; t >= 0; --t) {
    // draw setup for step t-1
    uint32_t gk0 = 0, gk1 = 0;
    float* nd = nullptr;
    if (t > 0) {
      gk0 = su[(t - 1) * 8 + 5];
      gk1 = su[(t - 1) * 8 + 6];
      nd = nb_w + ((t - 1) & 1) * 16 * NBW;
    }

    float sr = 0.f, srm1 = 0.f, c1 = 0.f, c2 = 0.f, sg = 0.f, tpn = 0.f;
    f32x4 acc;

    if (gemv) {
      sr   = sched[t * 8 + 0];
      srm1 = sched[t * 8 + 1];
      c1   = sched[t * 8 + 2];
      c2   = sched[t * 8 + 3];
      sg   = sched[t * 8 + 4];

      // ---- phase A: in-GEMV, full K=64, bias in all 4 owned slots
#pragma unroll
      for (int r = 0; r < 4; ++r) acc[r] = tp + cp[r];
      {
        short8 xh0 = ld_frag16(&Xh[arow * XLDW + kq0]);
        short8 xl0 = ld_frag16(&Xl[arow * XLDW + kq0]);
        short8 xh1 = ld_frag16(&Xh[arow * XLDW + kq1]);
        short8 xl1 = ld_frag16(&Xl[arow * XLDW + kq1]);
        acc = __builtin_amdgcn_mfma_f32_16x16x32_bf16(xl0, wiH0, acc, 0, 0, 0);
        acc = __builtin_amdgcn_mfma_f32_16x16x32_bf16(xh0, wiL0, acc, 0, 0, 0);
        acc = __builtin_amdgcn_mfma_f32_16x16x32_bf16(xh0, wiH0, acc, 0, 0, 0);
        acc = __builtin_amdgcn_mfma_f32_16x16x32_bf16(xl1, wiH1, acc, 0, 0, 0);
        acc = __builtin_amdgcn_mfma_f32_16x16x32_bf16(xh1, wiL1, acc, 0, 0, 0);
        acc = __builtin_amdgcn_mfma_f32_16x16x32_bf16(xh1, wiH1, acc, 0, 0, 0);
      }
#pragma unroll
      for (int r = 0; r < 4; ++r) {
        float v = acc[r];
        v = v * __builtin_amdgcn_rcpf(1.0f + __expf(-v));
        short h, l;
        split_bf16(v, h, l);
        Hh[(rowb + r) * XLDW + dim] = h; Hl[(rowb + r) * XLDW + dim] = l;
      }
      int tn = (t > 0) ? (t - 1) : 0;
      tpn = tpb[tn * 64 + dim];                    // prefetch next tp
    }
    // segA (all 8 waves): BOTH threefry chains for step t-1 (bits only,
    // ILP-2); erfinv deferred to segB. Bits carried across B1 in 2 regs.
    uint32_t b0 = 0, b1 = 0;
    if (t > 0) {
      b0 = jax_random_bits32(gk0, gk1, jn + 0u);
      b1 = jax_random_bits32(gk0, gk1, jn + 1u);
    }
    __syncthreads();                                // B1

    if (gemv) {
      // noise for this step (buf t&1 fully written by end of iter t+1)
      float n[4];
      const float* nr = &nbuf[(t & 1) * 16 * NBW + rowb * NBW + dim];
#pragma unroll
      for (int r = 0; r < 4; ++r) n[r] = nr[r * NBW];

      // ---- phase B: out-GEMV, full K=64, update 4 cells, restage X
      f32x4 eac;
#pragma unroll
      for (int r = 0; r < 4; ++r) eac[r] = bo;
      {
        short8 hh0 = ld_frag16(&Hh[arow * XLDW + kq0]);
        short8 hl0 = ld_frag16(&Hl[arow * XLDW + kq0]);
        short8 hh1 = ld_frag16(&Hh[arow * XLDW + kq1]);
        short8 hl1 = ld_frag16(&Hl[arow * XLDW + kq1]);
        eac = __builtin_amdgcn_mfma_f32_16x16x32_bf16(hl0, woH0, eac, 0, 0, 0);
        eac = __builtin_amdgcn_mfma_f32_16x16x32_bf16(hh0, woL0, eac, 0, 0, 0);
        eac = __builtin_amdgcn_mfma_f32_16x16x32_bf16(hh0, woH0, eac, 0, 0, 0);
        eac = __builtin_amdgcn_mfma_f32_16x16x32_bf16(hl1, woH1, eac, 0, 0, 0);
        eac = __builtin_amdgcn_mfma_f32_16x16x32_bf16(hh1, woL1, eac, 0, 0, 0);
        eac = __builtin_amdgcn_mfma_f32_16x16x32_bf16(hh1, woH1, eac, 0, 0, 0);
      }
#pragma unroll
      for (int r = 0; r < 4; ++r) {
        float xc = fminf(1.f, fmaxf(-1.f, sr * xo[r] - srm1 * eac[r]));
        xo[r] = c1 * xc + c2 * xo[r] + sg * n[r];
        short h, l;
        split_bf16(xo[r], h, l);
        Xh[(rowb + r) * XLDW + dim] = h; Xl[(rowb + r) * XLDW + dim] = l;
      }
      tp = tpn;
    }
    // segB (all 8 waves): BOTH erfinv chains (ILP-2) + nbuf write.
    // Written before B2(t); consumed after B1(t-1) -> safe.
    if (t > 0) {
      nd[0] = jax_bits_to_normal(b0);
      nd[1] = jax_bits_to_normal(b1);
    }
    __syncthreads();                                // B2
  }

  if (gemv) {
#pragma unroll
    for (int r = 0; r < 4; ++r) out[j0 + r * 64u] = xo[r];
  }
}

// ---------------------------------------------------------------------------
extern "C" void kernel_launch(void* const* d_in, const int* in_sizes, int n_in,
                              void* d_out, int out_size, void* d_ws, size_t ws_size,
                              hipStream_t stream)
{
  const int*   seq  = (const int*)  d_in[0];
  const float* emb  = (const float*)d_in[1];
  const float* W1   = (const float*)d_in[2];
  const float* b1   = (const float*)d_in[3];
  const float* W2   = (const float*)d_in[4];
  const float* b2   = (const float*)d_in[5];
  const float* Win  = (const float*)d_in[6];
  const float* bin  = (const float*)d_in[7];
  const float* Wt   = (const float*)d_in[8];
  const float* bt   = (const float*)d_in[9];
  const float* Wc   = (const float*)d_in[10];
  const float* bc   = (const float*)d_in[11];
  const float* Wout = (const float*)d_in[12];
  const float* bout = (const float*)d_in[13];

  float* out   = (float*)d_out;
  float* ws    = (float*)d_ws;
  float* cproj = ws;                       // 524288 floats
  float* tpb   = ws + 524288;              // 12800 floats
  float* sched = ws + 524288 + 12800;      // 1600 floats (t*8 layout)
  float* pooled = out;                     // reuse d_out as scratch

  k_poolprep<<<2248, 256, 0, stream>>>(seq, emb, pooled, Wt, bt, bin, tpb, sched);
  k_enc  <<<1024, 256, 0, stream>>>(pooled, W1, b1, W2, b2, Wc, bc, cproj);
  k_ddpm <<<512, 512, 0, stream>>>(Win, Wout, bout, cproj, tpb, sched, out);
}